// Round 12
// baseline (360.549 us; speedup 1.0000x reference)
//
#include <hip/hip_runtime.h>

// VQ-VAE codebook quantization — MFMA-screened, np-bit-exact.
// Screen: split-bf16 (xh+xl)(ch+cl) via mfma_f32_16x16x32_bf16, 3 terms.
// Sound window W flags possible np-argmin ambiguity; flagged positions
// re-scanned with the exact np fp32 pipeline.
//
// R12: SELF-CALIBRATING ATTRIBUTION. R11 (clean, no spill) showed LDS-
// staging of B-frags is worth only ~3us -> L2-traffic theory mostly dead.
// Issue-cycle models predict ~25-30us for P1-P5; hardware says 78-98.
// Stop guessing: P3 is IDEMPOTENT (re-init m1/m2/t1 per rep -> identical
// result), so amplified variants stay bit-exact and rocprof reads the
// marginal cost in the true fused context:
//   A = vq_tmpl<4,true>  : P3 x4 (stage+compute each rep)  -> P3=(A-M)/3
//   B = vq_tmpl<4,false> : staging skeleton x4, compute on last rep only
//                          -> staging+sync=(B-M)/3, compute=(A-B)/3
//   M = vq_tmpl<1,true>  : exactly R11 (runs LAST, the product kernel)
// All three write the full correct output -> absmax 0 regardless.
// Validity: every row WRITE_SIZE==65536 KB, VGPR<=64.
// B comes from total-minus-known (overhead ~72us stable across R4/R6/R11).

typedef short bf16x8 __attribute__((ext_vector_type(8)));
typedef float f32x4  __attribute__((ext_vector_type(4)));

#define KCODES 512
#define DDIM 64
#define HWSZ 4096
#define NPOS 131072
#define POSB 128             // positions per block
#define NBLK (NPOS / POSB)   // 1024 = 256 CU x 4 blocks/CU (one resident round)
#define OUT2_OFF 8388608
#define S_X 132              // x_lds pos-stride in floats (mult of 4: aligned b128)
#define S_X4 (S_X / 4)       // float4 stride = 33

#define GLD_LDS16(gsrc, ldst)                                                   \
    __builtin_amdgcn_global_load_lds(                                           \
        (const __attribute__((address_space(1))) void*)(gsrc),                  \
        (__attribute__((address_space(3))) void*)(ldst), 16, 0, 0)

__device__ __forceinline__ unsigned short f2bf_rne(float f) {
    unsigned u = __builtin_bit_cast(unsigned, f);
    unsigned r = u + 0x7FFFu + ((u >> 16) & 1u);
    return (unsigned short)(r >> 16);
}
__device__ __forceinline__ float bf2f(unsigned short h) {
    unsigned u = ((unsigned)h) << 16;
    return __builtin_bit_cast(float, u);
}

// numpy pairwise_sum (n=64 branch) of rounded squares, fp32, no fma.
__device__ __forceinline__ float np_sumsq64(const float* __restrict__ a) {
#pragma clang fp contract(off)
    float r0 = a[0]*a[0], r1 = a[1]*a[1], r2 = a[2]*a[2], r3 = a[3]*a[3];
    float r4 = a[4]*a[4], r5 = a[5]*a[5], r6 = a[6]*a[6], r7 = a[7]*a[7];
#pragma unroll
    for (int i = 8; i < 64; i += 8) {
        r0 += a[i+0]*a[i+0]; r1 += a[i+1]*a[i+1];
        r2 += a[i+2]*a[i+2]; r3 += a[i+3]*a[i+3];
        r4 += a[i+4]*a[i+4]; r5 += a[i+5]*a[i+5];
        r6 += a[i+6]*a[i+6]; r7 += a[i+7]*a[i+7];
    }
    return ((r0+r1)+(r2+r3)) + ((r4+r5)+(r6+r7));
}

// Prep: B-fragments (split bf16) in exact 16x16x32 B-operand layout + np cbsqr.
__global__ __launch_bounds__(256) void vq_prep(
    const float* __restrict__ cb, unsigned short* __restrict__ wsb,
    float* __restrict__ wscb)
{
    if (blockIdx.x < 128) {
        int u = blockIdx.x * 256 + threadIdx.x;   // u = k*64 + d
        int k = u >> 6, d = u & 63;
        float c = cb[u];
        unsigned short ch = f2bf_rne(c);
        float clf = c - bf2f(ch);                  // exact
        unsigned short cl = f2bf_rne(clf);
        int tile = k >> 4, n = k & 15;
        int chunk = d >> 5, quad = (d >> 3) & 3, j = d & 7;
        int lane = quad * 16 + n;                  // B: lane holds B[k=q*8+j][n]
        size_t base = ((((size_t)tile*2 + chunk)*2 + 0)*64 + lane)*8 + j;
        wsb[base]       = (unsigned short)ch;
        wsb[base + 512] = (unsigned short)cl;      // split stride = 64*8
    } else {
        int k = (blockIdx.x - 128) * 256 + threadIdx.x;
        if (k < KCODES) wscb[k] = np_sumsq64(cb + k * DDIM);
    }
}

template <int NREP, bool CALL>
__global__ __launch_bounds__(256, 4) void vq_tmpl(
    const float* __restrict__ z, const float* __restrict__ cb,
    const unsigned short* __restrict__ wsb, const float* __restrict__ wscb,
    float* __restrict__ out)
{
#pragma clang fp contract(off)
    __shared__ float4 s_xbuf4[DDIM * S_X4];   // 33792 B: x tile -> frag staging -> codes
    __shared__ float s_cbsqr[KCODES];
    __shared__ float s_xsqr[POSB];
    __shared__ float s_part[2 * POSB];
    __shared__ int   s_idx[POSB];
    __shared__ int   s_flist[POSB];
    __shared__ int   s_cnt;
    float* s_regA = (float*)s_xbuf4;

    const int tid = threadIdx.x;
    const int wv = tid >> 6, ln = tid & 63;
    const int m = ln & 15, q = ln >> 4;
    const int n0 = blockIdx.x * POSB;
    const long gbase = (long)(n0 >> 12) * (DDIM * HWSZ) + (n0 & 4095);

    if (tid == 0) s_cnt = 0;
    s_cbsqr[tid] = wscb[tid];
    s_cbsqr[tid + 256] = wscb[tid + 256];

    // ---- phase 1: z -> x_lds, d-major [d][pos], float4 coalesced ----
    {
        const float4* z4 = (const float4*)(z + gbase);
#pragma unroll
        for (int i = 0; i < 8; ++i) {
            int v = i * 256 + tid;
            int d = v >> 5, p4 = v & 31;
            s_xbuf4[d * S_X4 + p4] = z4[d * (HWSZ / 4) + p4];
        }
    }
    __syncthreads();

    // ---- phase 2a: np xsqr partials (thread -> (p, h)) ----
    {
        int p = tid & 127, h = tid >> 7;
        float r0 = 0.f, r1 = 0.f, r2 = 0.f, r3 = 0.f;
#pragma unroll
        for (int i = 0; i < 8; ++i) {
            float a0 = s_regA[(8*i + 4*h + 0) * S_X + p];
            float a1 = s_regA[(8*i + 4*h + 1) * S_X + p];
            float a2 = s_regA[(8*i + 4*h + 2) * S_X + p];
            float a3 = s_regA[(8*i + 4*h + 3) * S_X + p];
            r0 += a0*a0; r1 += a1*a1; r2 += a2*a2; r3 += a3*a3;
        }
        s_part[h * POSB + p] = (r0 + r1) + (r2 + r3);
    }

    // ---- phase 2b: A-fragments (per wave: 2 row-tiles x 2 K-chunks, split) ----
    bf16x8 Ah[4], Al[4];
#pragma unroll
    for (int rt = 0; rt < 2; ++rt)
#pragma unroll
        for (int c = 0; c < 2; ++c) {
            int pos = wv * 32 + rt * 16 + m;
            bf16x8 ah, al;
#pragma unroll
            for (int j = 0; j < 8; ++j) {
                float xv = s_regA[(c*32 + q*8 + j) * S_X + pos];
                unsigned short hh = f2bf_rne(xv);
                float lo = xv - bf2f(hh);          // exact
                ah[j] = (short)hh;
                al[j] = (short)f2bf_rne(lo);
            }
            Ah[rt*2 + c] = ah; Al[rt*2 + c] = al;
        }
    __syncthreads();   // ALL x-tile reads complete -> buffer reusable for staging
    if (tid < POSB) s_xsqr[tid] = s_part[tid] + s_part[POSB + tid]; // np (A+B)
    // (published at the first in-loop barrier)

    // ---- phase 3: screen all 512 codes; LDS-staged per 4-tile chunk.
    //      NREP repetitions, re-initialized each rep -> idempotent, bit-exact.
    //      CALL=false: MFMA/min-track only on the last rep (staging skeleton
    //      still runs every rep). ----
    float m1[8], m2[8]; int t1[8];
    char* const stg = (char*)s_regA;             // 16 KB staging window

    for (int rep = 0; rep < NREP; ++rep) {
#pragma unroll
        for (int i = 0; i < 8; ++i) { m1[i] = 3.4e38f; m2[i] = 3.4e38f; t1[i] = 0; }
        const bool docomp = CALL || (rep == NREP - 1);
        for (int g = 0; g < 8; ++g) {
            {
                const unsigned short* src = wsb + (g * 4 + wv) * 2048 + ln * 8;
                char* dst = stg + wv * 4096;
#pragma unroll
                for (int i = 0; i < 4; ++i) GLD_LDS16(src + i * 512, dst + i * 1024);
            }
            asm volatile("s_waitcnt vmcnt(0)" ::: "memory");
            __syncthreads();   // chunk staged (first: also publishes s_xsqr)
            if (docomp) {
#pragma unroll
                for (int ti = 0; ti < 4; ++ti) {
                    int t = g * 4 + ti;
                    const unsigned short* sB =
                        (const unsigned short*)(stg + ti * 4096) + ln * 8;
                    float cbv = s_cbsqr[t * 16 + m];
                    f32x4 acc0 = {0.f, 0.f, 0.f, 0.f};
                    f32x4 acc1 = {0.f, 0.f, 0.f, 0.f};
                    bf16x8 Bh = *(const bf16x8*)(sB);
                    bf16x8 Bl = *(const bf16x8*)(sB + 512);
                    acc0 = __builtin_amdgcn_mfma_f32_16x16x32_bf16(Al[0], Bh, acc0, 0,0,0);
                    acc0 = __builtin_amdgcn_mfma_f32_16x16x32_bf16(Ah[0], Bl, acc0, 0,0,0);
                    acc0 = __builtin_amdgcn_mfma_f32_16x16x32_bf16(Ah[0], Bh, acc0, 0,0,0);
                    acc1 = __builtin_amdgcn_mfma_f32_16x16x32_bf16(Al[2], Bh, acc1, 0,0,0);
                    acc1 = __builtin_amdgcn_mfma_f32_16x16x32_bf16(Ah[2], Bl, acc1, 0,0,0);
                    acc1 = __builtin_amdgcn_mfma_f32_16x16x32_bf16(Ah[2], Bh, acc1, 0,0,0);
                    Bh = *(const bf16x8*)(sB + 1024);
                    Bl = *(const bf16x8*)(sB + 1536);
                    acc0 = __builtin_amdgcn_mfma_f32_16x16x32_bf16(Al[1], Bh, acc0, 0,0,0);
                    acc0 = __builtin_amdgcn_mfma_f32_16x16x32_bf16(Ah[1], Bl, acc0, 0,0,0);
                    acc0 = __builtin_amdgcn_mfma_f32_16x16x32_bf16(Ah[1], Bh, acc0, 0,0,0);
                    acc1 = __builtin_amdgcn_mfma_f32_16x16x32_bf16(Al[3], Bh, acc1, 0,0,0);
                    acc1 = __builtin_amdgcn_mfma_f32_16x16x32_bf16(Ah[3], Bl, acc1, 0,0,0);
                    acc1 = __builtin_amdgcn_mfma_f32_16x16x32_bf16(Ah[3], Bh, acc1, 0,0,0);
#pragma unroll
                    for (int r = 0; r < 4; ++r) {
                        float sc = fmaf(-2.f, acc0[r], cbv);
                        bool lt = sc < m1[r];
                        m2[r] = fminf(m2[r], lt ? m1[r] : sc);
                        if (lt) { m1[r] = sc; t1[r] = t; }
                    }
#pragma unroll
                    for (int r = 0; r < 4; ++r) {
                        float sc = fmaf(-2.f, acc1[r], cbv);
                        int cell = 4 + r;
                        bool lt = sc < m1[cell];
                        m2[cell] = fminf(m2[cell], lt ? m1[cell] : sc);
                        if (lt) { m1[cell] = sc; t1[cell] = t; }
                    }
                }
            }
            __syncthreads();   // all waves done with chunk before overwrite
        }
    }

    // ---- phase 4: per-position reduce over 16 lanes; flag ambiguity ----
#pragma unroll
    for (int cell = 0; cell < 8; ++cell) {
        int rt = cell >> 2, r = cell & 3;
        float v1 = m1[cell], v2 = m2[cell];
        int i1 = t1[cell] * 16 + m;
#pragma unroll
        for (int s = 1; s < 16; s <<= 1) {
            float o1 = __shfl_xor(v1, s);
            float o2 = __shfl_xor(v2, s);
            int   oi = __shfl_xor(i1, s);
            bool take = (o1 < v1) || (o1 == v1 && oi < i1);
            float lose = take ? v1 : o1;
            if (take) { v1 = o1; i1 = oi; }
            v2 = fminf(fminf(v2, o2), lose);
        }
        if (m == 0) {
            int pos = wv * 32 + rt * 16 + q * 4 + r;
            float xs = s_xsqr[pos];
            float sx = 8.0f * sqrtf(xs) * 1.01f;       // >= sum |x_d|
            float amax = 0.00196f * sx + 0.01f;        // >= sum|x c| + margin
            float eps = 1.5f * (3.0f * 1.52587890625e-5f * 0.00196f * sx
                                + 500.f * 5.96e-8f * amax);
            float delta = 2.4e-7f * (xs + 1.0f) + 64.f * 1.2e-7f * amax;
            float W = 2.f * eps + 2.f * delta + 1e-9f;
            int flag = (v2 - v1 <= W) ? (1 << 30) : 0;
            s_idx[pos] = i1 | flag;
        }
    }
    __syncthreads();
    if (tid < POSB) {
        if (s_idx[tid] & (1 << 30)) {
            int slot = atomicAdd(&s_cnt, 1);
            s_flist[slot] = tid;
        }
    }
    __syncthreads();

    // ---- phase 5: np-exact refine of flagged positions (x from global z) ----
    const int cnt = s_cnt;
    for (int i = wv; i < cnt; i += 4) {
        int p = __builtin_amdgcn_readfirstlane(s_flist[i]);
        float xv = z[gbase + (long)ln * HWSZ + p];   // lane ln holds x[d=ln]
        float xs = s_xsqr[p];
        float dot[8];
#pragma unroll
        for (int j = 0; j < 8; ++j) dot[j] = 0.f;
        const float* crow = cb + (ln * 8) * DDIM;    // lane's 8 codes
        for (int dc = 0; dc < 16; ++dc) {
            float x0 = __shfl(xv, dc*4 + 0);
            float x1 = __shfl(xv, dc*4 + 1);
            float x2 = __shfl(xv, dc*4 + 2);
            float x3 = __shfl(xv, dc*4 + 3);
#pragma unroll
            for (int j = 0; j < 8; ++j) {
                float4 cv = *(const float4*)(crow + j * DDIM + dc * 4);
                dot[j] = fmaf(x0, cv.x, dot[j]);
                dot[j] = fmaf(x1, cv.y, dot[j]);
                dot[j] = fmaf(x2, cv.z, dot[j]);
                dot[j] = fmaf(x3, cv.w, dot[j]);
            }
        }
        float bv = 3.4e38f; int bi = 0;
#pragma unroll
        for (int j = 0; j < 8; ++j) {
            int k = ln * 8 + j;
            float tt = s_cbsqr[k] + xs;
            float e = fmaf(-2.f, dot[j], tt);
            if (e < bv) { bv = e; bi = k; }
        }
#pragma unroll
        for (int s = 1; s < 64; s <<= 1) {
            float ov = __shfl_xor(bv, s); int oi = __shfl_xor(bi, s);
            if (ov < bv || (ov == bv && oi < bi)) { bv = ov; bi = oi; }
        }
        if (ln == 0) s_idx[p] = bi;
    }
    __syncthreads();   // s_idx final -> safe to overwrite s_regA

    // ---- phase 6a: stage selected code rows into LDS, d-major [d][pos] ----
    {
        int p = tid & 127, hf = tid >> 7;
        int idx = s_idx[p] & 0x3FFFFFFF;
        const float4* crow4 = (const float4*)(cb + idx * DDIM + hf * 32);
#pragma unroll
        for (int j4 = 0; j4 < 8; ++j4) {
            float4 cv = crow4[j4];
            int d = hf * 32 + j4 * 4;
            s_regA[(d + 0) * S_X + p] = cv.x;
            s_regA[(d + 1) * S_X + p] = cv.y;
            s_regA[(d + 2) * S_X + p] = cv.z;
            s_regA[(d + 3) * S_X + p] = cv.w;
        }
    }
    __syncthreads();

    // ---- phase 6b: float4 writeback to both outputs (NCHW) ----
    {
        float4* o4 = (float4*)(out + gbase);
#pragma unroll
        for (int i = 0; i < 8; ++i) {
            int v = i * 256 + tid;
            int d = v >> 5, p4 = v & 31;
            float4 val = s_xbuf4[d * S_X4 + p4];
            size_t off = (size_t)d * (HWSZ / 4) + p4;
            o4[off] = val;
            o4[off + (OUT2_OFF / 4)] = val;
        }
    }
}

extern "C" void kernel_launch(void* const* d_in, const int* in_sizes, int n_in,
                              void* d_out, int out_size, void* d_ws, size_t ws_size,
                              hipStream_t stream) {
    const float* z  = (const float*)d_in[0];   // [32,64,64,64] fp32
    const float* cb = (const float*)d_in[1];   // [512,64] fp32
    float* out = (float*)d_out;                // 2 * 8388608 fp32
    unsigned short* wsb = (unsigned short*)d_ws;            // 128 KB frags
    float* wscb = (float*)((char*)d_ws + 131072);           // 2 KB cbsqr
    vq_prep<<<130, 256, 0, stream>>>(cb, wsb, wscb);
    // A: P3 x4 (stage+compute each rep)          -> P3_total = (A - M)/3
    vq_tmpl<4, true><<<NBLK, 256, 0, stream>>>(z, cb, wsb, wscb, out);
    // B: staging skeleton x4, compute last rep   -> staging+sync = (B - M)/3
    vq_tmpl<4, false><<<NBLK, 256, 0, stream>>>(z, cb, wsb, wscb, out);
    // M: the product kernel (R11), runs last -> final correct output
    vq_tmpl<1, true><<<NBLK, 256, 0, stream>>>(z, cb, wsb, wscb, out);
}